// Round 1
// baseline (159.796 us; speedup 1.0000x reference)
//
#include <hip/hip_runtime.h>
#include <stdint.h>

// Attention_65962107732002: per-head attention, B=4 S=1024 H=12 DM=768 DH=64.
// Pipeline: prep (transpose weights to bf16) -> qkv_gemm (bf16 MFMA, writes
// q,k(,/8),vT bf16 to ws) -> attn_fwd (flash, f32 softmax) -> o_gemm (f32 out).
// All LDS tiles are 128B rows with XOR swizzle byte^=((row&7)<<4); staging via
// global_load_lds uses pre-swizzled global source addresses (linear LDS dest).

#define B_ 4
#define S_ 1024
#define H_ 12
#define DM_ 768
#define DH_ 64
#define BH_ (B_*H_)

typedef float floatx4 __attribute__((ext_vector_type(4)));
typedef __bf16 bfx8 __attribute__((ext_vector_type(8)));

static __device__ __forceinline__ uint16_t f2bf(float f) {
  union { float f; uint32_t u; } v; v.f = f;
  return (uint16_t)((v.u + 0x7FFFu + ((v.u >> 16) & 1u)) >> 16);  // RNE
}

static __device__ __forceinline__ floatx4 mfma16(bfx8 a, bfx8 b, floatx4 c) {
  return __builtin_amdgcn_mfma_f32_16x16x32_bf16(a, b, c, 0, 0, 0);
}

static __device__ __forceinline__ void gload_lds16(const void* g, void* l) {
  __builtin_amdgcn_global_load_lds(
      (const __attribute__((address_space(1))) uint32_t*)g,
      (__attribute__((address_space(3))) uint32_t*)l, 16, 0, 0);
}

// ---------------- prep: transpose weights to bf16 ----------------
// wt_qkv[mi][h][d][m] = W_mi[h][m][d]   (K pre-scaled by 1/8)
// wt_o  [h][m][d]     = W_O [h][d][m]
__global__ __launch_bounds__(256) void prep_weights(
    const float* __restrict__ Wq, const float* __restrict__ Wk,
    const float* __restrict__ Wv, const float* __restrict__ Wo,
    uint16_t* __restrict__ wt_qkv, uint16_t* __restrict__ wt_o) {
  const int total = H_ * DM_ * DH_;  // 589824
  for (int i = blockIdx.x * blockDim.x + threadIdx.x; i < total;
       i += gridDim.x * blockDim.x) {
    int d = i % DH_;
    int m = (i / DH_) % DM_;
    int h = i / (DH_ * DM_);
    size_t o = (((size_t)h) * DH_ + d) * DM_ + m;
    wt_qkv[o] = f2bf(Wq[i]);
    wt_qkv[(size_t)H_ * DH_ * DM_ + o] = f2bf(Wk[i] * 0.125f);
    wt_qkv[2 * (size_t)H_ * DH_ * DM_ + o] = f2bf(Wv[i]);
  }
  for (int i = blockIdx.x * blockDim.x + threadIdx.x; i < total;
       i += gridDim.x * blockDim.x) {
    int m = i % DM_;
    int d = (i / DM_) % DH_;
    int h = i / (DM_ * DH_);
    wt_o[(((size_t)h) * DM_ + m) * DH_ + d] = f2bf(Wo[i]);
  }
}

// ---------------- QKV projection ----------------
// Block: 64 bs-rows x one head x 192 cols (q|k|v). 4 waves, each 64x48.
__global__ __launch_bounds__(256) void qkv_gemm(
    const float* __restrict__ x, const float* __restrict__ bq,
    const float* __restrict__ bk, const float* __restrict__ bv,
    const uint16_t* __restrict__ wt_qkv,
    uint16_t* __restrict__ q_ws, uint16_t* __restrict__ k_ws,
    uint16_t* __restrict__ vT_ws) {
  __shared__ __align__(16) uint16_t Al[64 * 64];   // [row][k] swizzled
  __shared__ __align__(16) uint16_t Bl[192 * 64];  // [n(3x64)][k] swizzled
  const int tid = threadIdx.x;
  const int lane = tid & 63;
  const int wv = tid >> 6;
  const int tile = blockIdx.x & 63;
  const int h = blockIdx.x >> 6;
  const int row0 = tile * 64;

  floatx4 acc[4][3];
#pragma unroll
  for (int i = 0; i < 4; ++i)
#pragma unroll
    for (int j = 0; j < 3; ++j) acc[i][j] = (floatx4){0.f, 0.f, 0.f, 0.f};

  const int ar = tid >> 4;         // 0..15 (row within pass)
  const int ak = (tid & 15) << 2;  // k start (0..60, step 4)
  const float* xbase = x + (size_t)row0 * H_ * DM_ + h * DM_;

  for (int kt = 0; kt < 12; ++kt) {
    __syncthreads();
    // A stage: x f32 -> bf16, swizzled LDS
#pragma unroll
    for (int rr = 0; rr < 4; ++rr) {
      int r = ar + rr * 16;
      const float* src = xbase + (size_t)r * H_ * DM_ + kt * 64 + ak;
      floatx4 v = *reinterpret_cast<const floatx4*>(src);
      uint64_t pk = (uint64_t)f2bf(v[0]) | ((uint64_t)f2bf(v[1]) << 16) |
                    ((uint64_t)f2bf(v[2]) << 32) | ((uint64_t)f2bf(v[3]) << 48);
      int byte = r * 128 + ((ak << 1) ^ ((r & 7) << 4));
      *reinterpret_cast<uint64_t*>((char*)Al + byte) = pk;
    }
    // B stage: wt_qkv (already bf16), global_load_lds with pre-swizzled src
#pragma unroll
    for (int it = 0; it < 6; ++it) {
      int rowbase = wv * 48 + it * 8;
      int r = rowbase + (lane >> 3);
      int slot = lane & 7;
      int mi = r >> 6, n = r & 63;
      const uint16_t* src = wt_qkv + (((size_t)mi * H_ + h) * DH_ + n) * DM_ +
                            kt * 64 + ((slot ^ (r & 7)) << 3);
      gload_lds16(src, (char*)Bl + rowbase * 128);
    }
    __syncthreads();
#pragma unroll
    for (int ks = 0; ks < 2; ++ks) {
      const int kb = ks * 64 + ((lane >> 4) << 4);
      bfx8 af[4], bfr[3];
#pragma unroll
      for (int fm = 0; fm < 4; ++fm) {
        int r = fm * 16 + (lane & 15);
        af[fm] = *reinterpret_cast<const bfx8*>((char*)Al + r * 128 +
                                                (kb ^ ((r & 7) << 4)));
      }
#pragma unroll
      for (int fn = 0; fn < 3; ++fn) {
        int r = wv * 48 + fn * 16 + (lane & 15);
        bfr[fn] = *reinterpret_cast<const bfx8*>((char*)Bl + r * 128 +
                                                 (kb ^ ((r & 7) << 4)));
      }
#pragma unroll
      for (int fm = 0; fm < 4; ++fm)
#pragma unroll
        for (int fn = 0; fn < 3; ++fn)
          acc[fm][fn] = mfma16(af[fm], bfr[fn], acc[fm][fn]);
    }
  }
  // epilogue: C/D layout col=lane&15 (n), row=(lane>>4)*4+reg (m)
  const int b = row0 >> 10;
  const int sbase = row0 & 1023;
  const int bh = b * H_ + h;
#pragma unroll
  for (int fn = 0; fn < 3; ++fn) {
    int ncol = wv * 48 + fn * 16 + (lane & 15);
    int mi = ncol >> 6, col = ncol & 63;
    const float* bp = (mi == 0) ? bq : (mi == 1 ? bk : bv);
    float bias = bp[h * DH_ + col];
    if (mi == 1) bias *= 0.125f;  // k_ws holds k/8
#pragma unroll
    for (int fm = 0; fm < 4; ++fm) {
#pragma unroll
      for (int r = 0; r < 4; ++r) {
        int s = sbase + fm * 16 + ((lane >> 4) << 2) + r;
        uint16_t o = f2bf(acc[fm][fn][r] + bias);
        if (mi == 0)
          q_ws[((size_t)bh * S_ + s) * DH_ + col] = o;
        else if (mi == 1)
          k_ws[((size_t)bh * S_ + s) * DH_ + col] = o;
        else
          vT_ws[((size_t)bh * DH_ + col) * S_ + s] = o;  // V transposed
      }
    }
  }
}

// ---------------- flash attention ----------------
// Block: (bh, q-tile of 128). 4 waves x 32 q-rows. KV tiles of 64, causal.
__global__ __launch_bounds__(256) void attn_fwd(
    const uint16_t* __restrict__ q_ws, const uint16_t* __restrict__ k_ws,
    const uint16_t* __restrict__ vT_ws, uint16_t* __restrict__ z_ws) {
  __shared__ __align__(16) uint16_t Kl[64 * 64];      // [kv][d] swizzled
  __shared__ __align__(16) uint16_t Vl[64 * 64];      // [d][kv] swizzled
  __shared__ __align__(16) uint16_t Pl[4][32 * 64];   // per-wave [q][kv]
  const int tid = threadIdx.x, lane = tid & 63, wv = tid >> 6;
  const int bh = blockIdx.x % (BH_);
  const int qt = 7 - blockIdx.x / (BH_);  // heavy tiles first
  const int q0 = qt * 128;
  const int qw0 = q0 + wv * 32;
  const uint16_t* qb = q_ws + (size_t)bh * S_ * DH_;
  const uint16_t* kbp = k_ws + (size_t)bh * S_ * DH_;
  const uint16_t* vbp = vT_ws + (size_t)bh * DH_ * S_;

  // Q fragments in registers (k_ws already scaled by 1/8, so no score scale)
  bfx8 qf[2][2];
#pragma unroll
  for (int fm = 0; fm < 2; ++fm)
#pragma unroll
    for (int ks = 0; ks < 2; ++ks) {
      int row = qw0 + fm * 16 + (lane & 15);
      int d = ks * 32 + ((lane >> 4) << 3);
      qf[fm][ks] = *reinterpret_cast<const bfx8*>(qb + (size_t)row * DH_ + d);
    }

  floatx4 accO[2][4];
  float mrun[2][4], lrun[2][4];
#pragma unroll
  for (int fm = 0; fm < 2; ++fm) {
#pragma unroll
    for (int fd = 0; fd < 4; ++fd) accO[fm][fd] = (floatx4){0.f, 0.f, 0.f, 0.f};
#pragma unroll
    for (int r = 0; r < 4; ++r) { mrun[fm][r] = -1e30f; lrun[fm][r] = 0.f; }
  }

  const int ntiles = qt * 2 + 2;
  for (int t = 0; t < ntiles; ++t) {
    const int kv0 = t * 64;
    __syncthreads();
#pragma unroll
    for (int it = 0; it < 2; ++it) {
      int rowbase = wv * 16 + it * 8;
      int r = rowbase + (lane >> 3);
      int slot = lane & 7;
      gload_lds16(kbp + (size_t)(kv0 + r) * DH_ + ((slot ^ (r & 7)) << 3),
                  (char*)Kl + rowbase * 128);
      gload_lds16(vbp + (size_t)r * S_ + kv0 + ((slot ^ (r & 7)) << 3),
                  (char*)Vl + rowbase * 128);
    }
    __syncthreads();
    if (kv0 > qw0 + 31) continue;  // fully masked for this wave

    // scores = Q K^T (A=Q, B=K rows)
    floatx4 sc[2][4];
#pragma unroll
    for (int fm = 0; fm < 2; ++fm)
#pragma unroll
      for (int fn = 0; fn < 4; ++fn) sc[fm][fn] = (floatx4){0.f, 0.f, 0.f, 0.f};
#pragma unroll
    for (int ks = 0; ks < 2; ++ks) {
      const int kb = ks * 64 + ((lane >> 4) << 4);
      bfx8 kf[4];
#pragma unroll
      for (int fn = 0; fn < 4; ++fn) {
        int r = fn * 16 + (lane & 15);
        kf[fn] = *reinterpret_cast<const bfx8*>((char*)Kl + r * 128 +
                                                (kb ^ ((r & 7) << 4)));
      }
#pragma unroll
      for (int fm = 0; fm < 2; ++fm)
#pragma unroll
        for (int fn = 0; fn < 4; ++fn)
          sc[fm][fn] = mfma16(qf[fm][ks], kf[fn], sc[fm][fn]);
    }
    // causal mask (same -1e5 as reference; exp underflows to 0 identically)
    if (kv0 + 63 > qw0) {
#pragma unroll
      for (int fm = 0; fm < 2; ++fm)
#pragma unroll
        for (int fn = 0; fn < 4; ++fn) {
          int qg = qw0 + fm * 16 + ((lane >> 4) << 2);
          int kvg = kv0 + fn * 16 + (lane & 15);
#pragma unroll
          for (int r = 0; r < 4; ++r)
            if (kvg > qg + r) sc[fm][fn][r] = -100000.0f;
        }
    }
    // online softmax (rows live on the 16-lane group lane&15)
#pragma unroll
    for (int fm = 0; fm < 2; ++fm) {
      float fsc[4], rsum[4];
#pragma unroll
      for (int r = 0; r < 4; ++r) {
        float m0 = fmaxf(fmaxf(sc[fm][0][r], sc[fm][1][r]),
                         fmaxf(sc[fm][2][r], sc[fm][3][r]));
#pragma unroll
        for (int off = 1; off < 16; off <<= 1)
          m0 = fmaxf(m0, __shfl_xor(m0, off, 64));
        float mnew = fmaxf(mrun[fm][r], m0);
        fsc[r] = __expf(mrun[fm][r] - mnew);
        mrun[fm][r] = mnew;
        rsum[r] = 0.f;
      }
#pragma unroll
      for (int fn = 0; fn < 4; ++fn)
#pragma unroll
        for (int r = 0; r < 4; ++r) {
          float p = __expf(sc[fm][fn][r] - mrun[fm][r]);
          sc[fm][fn][r] = p;
          rsum[r] += p;
        }
#pragma unroll
      for (int r = 0; r < 4; ++r) {
#pragma unroll
        for (int off = 1; off < 16; off <<= 1)
          rsum[r] += __shfl_xor(rsum[r], off, 64);
        lrun[fm][r] = lrun[fm][r] * fsc[r] + rsum[r];
      }
#pragma unroll
      for (int fd = 0; fd < 4; ++fd)
#pragma unroll
        for (int r = 0; r < 4; ++r) accO[fm][fd][r] *= fsc[r];
      // P -> LDS (bf16, swizzled) for the PV A-operand
#pragma unroll
      for (int fn = 0; fn < 4; ++fn)
#pragma unroll
        for (int r = 0; r < 4; ++r) {
          int ql = fm * 16 + ((lane >> 4) << 2) + r;
          int kv = fn * 16 + (lane & 15);
          int byte = ql * 128 + ((kv << 1) ^ ((ql & 7) << 4));
          *(uint16_t*)((char*)Pl[wv] + byte) = f2bf(sc[fm][fn][r]);
        }
    }
    // PV: A=P (rows q), B=vT (rows d)
#pragma unroll
    for (int ks = 0; ks < 2; ++ks) {
      const int kb = ks * 64 + ((lane >> 4) << 4);
      bfx8 pf[2], vf[4];
#pragma unroll
      for (int fm = 0; fm < 2; ++fm) {
        int r = fm * 16 + (lane & 15);
        pf[fm] = *reinterpret_cast<const bfx8*>((char*)Pl[wv] + r * 128 +
                                                (kb ^ ((r & 7) << 4)));
      }
#pragma unroll
      for (int fd = 0; fd < 4; ++fd) {
        int r = fd * 16 + (lane & 15);
        vf[fd] = *reinterpret_cast<const bfx8*>((char*)Vl + r * 128 +
                                                (kb ^ ((r & 7) << 4)));
      }
#pragma unroll
      for (int fm = 0; fm < 2; ++fm)
#pragma unroll
        for (int fd = 0; fd < 4; ++fd)
          accO[fm][fd] = mfma16(pf[fm], vf[fd], accO[fm][fd]);
    }
  }
  // epilogue: z = accO / lrun
#pragma unroll
  for (int fm = 0; fm < 2; ++fm)
#pragma unroll
    for (int r = 0; r < 4; ++r) {
      float inv = 1.0f / lrun[fm][r];
      int sg = qw0 + fm * 16 + ((lane >> 4) << 2) + r;
      uint16_t* dst = z_ws + ((size_t)bh * S_ + sg) * DH_;
#pragma unroll
      for (int fd = 0; fd < 4; ++fd) {
        int d = fd * 16 + (lane & 15);
        dst[d] = f2bf(accO[fm][fd][r] * inv);
      }
    }
}

// ---------------- output projection ----------------
// Block: 64 s-rows x 256 dm-cols for one head. K=64 single tile.
__global__ __launch_bounds__(256) void o_gemm(
    const uint16_t* __restrict__ z_ws, const uint16_t* __restrict__ wt_o,
    const float* __restrict__ bo, float* __restrict__ out) {
  __shared__ __align__(16) uint16_t Al[64 * 64];    // [s][d] swizzled
  __shared__ __align__(16) uint16_t Bl[256 * 64];   // [m][d] swizzled
  const int tid = threadIdx.x, lane = tid & 63, wv = tid >> 6;
  const int blk = blockIdx.x;
  const int nt = blk % 3;
  const int h = (blk / 3) % H_;
  const int tile = blk / (3 * H_);
  const int row0 = tile * 64;
  const int b = row0 >> 10, s0 = row0 & 1023;
  const int bh = b * H_ + h;
  const int n0 = nt * 256;
#pragma unroll
  for (int it = 0; it < 2; ++it) {
    int rowbase = wv * 16 + it * 8;
    int r = rowbase + (lane >> 3), slot = lane & 7;
    gload_lds16(z_ws + ((size_t)bh * S_ + s0 + r) * DH_ + ((slot ^ (r & 7)) << 3),
                (char*)Al + rowbase * 128);
  }
#pragma unroll
  for (int it = 0; it < 8; ++it) {
    int rowbase = wv * 64 + it * 8;
    int r = rowbase + (lane >> 3), slot = lane & 7;
    gload_lds16(wt_o + ((size_t)h * DM_ + n0 + r) * DH_ + ((slot ^ (r & 7)) << 3),
                (char*)Bl + rowbase * 128);
  }
  __syncthreads();
  floatx4 acc[4][4];
#pragma unroll
  for (int i = 0; i < 4; ++i)
#pragma unroll
    for (int j = 0; j < 4; ++j) acc[i][j] = (floatx4){0.f, 0.f, 0.f, 0.f};
#pragma unroll
  for (int ks = 0; ks < 2; ++ks) {
    const int kb = ks * 64 + ((lane >> 4) << 4);
    bfx8 af[4], bfr[4];
#pragma unroll
    for (int fm = 0; fm < 4; ++fm) {
      int r = fm * 16 + (lane & 15);
      af[fm] = *reinterpret_cast<const bfx8*>((char*)Al + r * 128 +
                                              (kb ^ ((r & 7) << 4)));
    }
#pragma unroll
    for (int fn = 0; fn < 4; ++fn) {
      int r = wv * 64 + fn * 16 + (lane & 15);
      bfr[fn] = *reinterpret_cast<const bfx8*>((char*)Bl + r * 128 +
                                               (kb ^ ((r & 7) << 4)));
    }
#pragma unroll
    for (int fm = 0; fm < 4; ++fm)
#pragma unroll
      for (int fn = 0; fn < 4; ++fn)
        acc[fm][fn] = mfma16(af[fm], bfr[fn], acc[fm][fn]);
  }
#pragma unroll
  for (int fn = 0; fn < 4; ++fn) {
    int m = n0 + wv * 64 + fn * 16 + (lane & 15);
    float bias = bo[m] / 12.0f;  // b_O / H, per reference
#pragma unroll
    for (int fm = 0; fm < 4; ++fm) {
      int sb = s0 + fm * 16 + ((lane >> 4) << 2);
#pragma unroll
      for (int r = 0; r < 4; ++r)
        out[(((size_t)b * S_ + sb + r) * H_ + h) * DM_ + m] =
            acc[fm][fn][r] + bias;
    }
  }
}

extern "C" void kernel_launch(void* const* d_in, const int* in_sizes, int n_in,
                              void* d_out, int out_size, void* d_ws,
                              size_t ws_size, hipStream_t stream) {
  (void)in_sizes; (void)n_in; (void)out_size; (void)ws_size;
  const float* x = (const float*)d_in[0];
  const float* Wq = (const float*)d_in[1];
  const float* bq = (const float*)d_in[2];
  const float* Wk = (const float*)d_in[3];
  const float* bk = (const float*)d_in[4];
  const float* Wv = (const float*)d_in[5];
  const float* bv = (const float*)d_in[6];
  const float* Wo = (const float*)d_in[7];
  const float* bo = (const float*)d_in[8];
  float* out = (float*)d_out;

  // workspace layout (bf16 = uint16): ~29.9 MB total
  uint16_t* wt_qkv = (uint16_t*)d_ws;                       // [3][12][64][768]
  uint16_t* wt_o = wt_qkv + (size_t)3 * H_ * DH_ * DM_;     // [12][768][64]
  uint16_t* q_ws = wt_o + (size_t)H_ * DM_ * DH_;           // [48][1024][64]
  uint16_t* k_ws = q_ws + (size_t)BH_ * S_ * DH_;           // [48][1024][64]
  uint16_t* vT_ws = k_ws + (size_t)BH_ * S_ * DH_;          // [48][64][1024]
  uint16_t* z_ws = vT_ws + (size_t)BH_ * DH_ * S_;          // [48][1024][64]

  prep_weights<<<1024, 256, 0, stream>>>(Wq, Wk, Wv, Wo, wt_qkv, wt_o);
  qkv_gemm<<<64 * H_, 256, 0, stream>>>(x, bq, bk, bv, wt_qkv, q_ws, k_ws, vT_ws);
  attn_fwd<<<BH_ * 8, 256, 0, stream>>>(q_ws, k_ws, vT_ws, z_ws);
  o_gemm<<<64 * H_ * 3, 256, 0, stream>>>(z_ws, wt_o, bo, out);
}